// Round 5
// baseline (188.903 us; speedup 1.0000x reference)
//
#include <hip/hip_runtime.h>

typedef _Float16 half_t;
typedef _Float16 half8  __attribute__((ext_vector_type(8)));
typedef _Float16 half4v __attribute__((ext_vector_type(4)));
typedef float    f32x16 __attribute__((ext_vector_type(16)));
typedef float    f32x4  __attribute__((ext_vector_type(4)));

#define DEVI static __device__ __forceinline__

constexpr int B_  = 16384;
constexpr int T_  = 28;
constexpr int IN_ = 28;
constexpr int H_  = 128;
constexpr int C_  = 11;
constexpr int BT  = 64;    // batch rows per block; grid = 256 = 1 block/CU
constexpr int NT  = 768;   // 12 waves: 4x L0, 4x L1, 4x L2
constexpr int HSTR = 136;  // LDS stride (halves): 272B rows, conflict-free b128
constexpr int XSTR = 40;

constexpr int HBUF = BT * HSTR;                 // 8704 halves per h buffer
constexpr int XBUF = BT * XSTR;                 // 2560 halves per x buffer
// rings: h0 x3, h1 x3, h2 x2, x x2
constexpr int SM_HALVES = 8 * HBUF + 2 * XBUF;  // 74752 halves
constexpr size_t SM_BYTES = (size_t)SM_HALVES * 2 + 3 * H_ * 4 + 64;  // 151104 B

DEVI f32x16 mfma(half8 a, half8 b, f32x16 c) {
  return __builtin_amdgcn_mfma_f32_32x32x16_f16(a, b, c, 0, 0, 0);
}

DEVI half8 frag(const half_t* base, int kc) { return *(const half8*)(base + kc * 16); }

// A-fragments, one 32-row m-tile of a 128x128 row-major fp32 matrix.
// A layout (32x32x16 f16, validated): lane holds A[m=lane&31][k=(lane>>5)*8+j].
DEVI void loadw8(half8 d[8], const float* __restrict__ w, int mrow, int hf) {
  const float* p = w + mrow * H_ + hf * 8;
#pragma unroll
  for (int kc = 0; kc < 8; ++kc) {
    half8 f;
#pragma unroll
    for (int j = 0; j < 8; ++j) f[j] = (half_t)p[kc * 16 + j];
    d[kc] = f;
  }
}

// One C-tile epilogue: h = relu(acc + bias) -> hout[b=ncol0+l31][n=mrow0+...].
// C/D layout (HW-verified m74/m101): col=lane&31, row=(reg&3)+8*(reg>>2)+4*(lane>>5).
DEVI void epi1(half_t* __restrict__ hout, const float* __restrict__ bl,
               f32x16 a, int mrow0, int ncol0, int l31, int hf) {
#pragma unroll
  for (int rq = 0; rq < 4; ++rq) {
    const int n0 = mrow0 + rq * 8 + hf * 4;
    const f32x4 b4 = *(const f32x4*)&bl[n0];
    half4v h4;
#pragma unroll
    for (int ri = 0; ri < 4; ++ri)
      h4[ri] = (half_t)fmaxf(a[rq * 4 + ri] + b4[ri], 0.0f);
    *(half4v*)&hout[(ncol0 + l31) * HSTR + n0] = h4;
  }
}

// ---- LDS flag sync (acquire/release) ----
// Producer: data ds_writes -> lgkmcnt(0) -> flag store. Consumer: spin on flag,
// then (memory clobber) data reads. LDS is physically shared per-CU; a flag
// value >= tgt implies the producer's prior writes are visible.
DEVI void wait4(volatile unsigned* f, int tgt) {
  if (tgt <= 0) return;
  for (;;) {
    unsigned a = f[0], b = f[1], c = f[2], d = f[3];
    if ((int)a >= tgt && (int)b >= tgt && (int)c >= tgt && (int)d >= tgt) break;
    __builtin_amdgcn_s_sleep(1);
  }
  asm volatile("" ::: "memory");
}
DEVI void bump(volatile unsigned* f, int v, int lane) {
  asm volatile("s_waitcnt lgkmcnt(0)" ::: "memory");
  if (lane == 0) *f = (unsigned)v;
}

// R5: barrier-free dataflow pipeline. Each layer group (4 waves) runs its own
// timestep loop gated on per-wave LDS flags: f0/f1/f2[4] = completed steps.
// Rings: h0,h1 depth-3; h2 depth-2; x depth-2. Back-pressure waits protect
// slot overwrite. No __syncthreads in the main loop -> layers' LDS bursts,
// MFMAs, epilogues interleave instead of convoying.
__global__ __launch_bounds__(NT) __attribute__((amdgpu_waves_per_eu(3)))
void rnn_pipe(const float* __restrict__ x,
              const float* __restrict__ wih0, const float* __restrict__ whh0,
              const float* __restrict__ bih0, const float* __restrict__ bhh0,
              const float* __restrict__ wih1, const float* __restrict__ whh1,
              const float* __restrict__ bih1, const float* __restrict__ bhh1,
              const float* __restrict__ wih2, const float* __restrict__ whh2,
              const float* __restrict__ bih2, const float* __restrict__ bhh2,
              const float* __restrict__ fcw, const float* __restrict__ fcb,
              float* __restrict__ out)
{
  extern __shared__ __align__(16) char smraw[];
  half_t* hs   = (half_t*)smraw;
  float*  bias = (float*)(hs + SM_HALVES);
  volatile unsigned* F0 = (volatile unsigned*)(bias + 3 * H_);  // [0..3]
  volatile unsigned* F1 = F0 + 4;                                // [4..7]
  volatile unsigned* F2 = F0 + 8;                                // [8..11]
#define HB0(s) (hs + (s) * HBUF)
#define HB1(s) (hs + (3 + (s)) * HBUF)
#define HB2(s) (hs + (6 + (s)) * HBUF)
#define XB(b)  (hs + 8 * HBUF + (b) * XBUF)

  const int tid  = threadIdx.x;
  const int b0   = blockIdx.x * BT;
  const int lane = tid & 63;
  const int wid  = tid >> 6;
  const int l31  = lane & 31;
  const int hf   = lane >> 5;

  // ---- init: zero all LDS buffers (h_{-1}=0, pad cols=0), biases, flags ----
  for (int i = tid; i < SM_HALVES / 2; i += NT) ((unsigned int*)hs)[i] = 0u;
  if (tid < H_) {
    bias[tid]          = bih0[tid] + bhh0[tid];
    bias[H_ + tid]     = bih1[tid] + bhh1[tid];
    bias[2 * H_ + tid] = bih2[tid] + bhh2[tid];
  }
  if (tid < 16) ((volatile unsigned*)F0)[tid] = 0u;
  __syncthreads();
  if (tid < 512) {  // stage x[t=0] into XB(0): 64 rows x 7 f32x4 chunks
    const int row = tid >> 3, ch = tid & 7;
    if (ch < 7) {
      const f32x4 v = *(const f32x4*)(x + (size_t)(b0 + row) * (T_ * IN_) + ch * 4);
      half4v h4;
#pragma unroll
      for (int j = 0; j < 4; ++j) h4[j] = (half_t)v[j];
      *(half4v*)&XB(0)[row * XSTR + ch * 4] = h4;
    }
  }
  __syncthreads();

  // ===== dataflow pipeline: each group loops its own t = 0..T-1 =====
  if (wid < 4) {
    // ---- L0: h0[t] = relu(b0 + x[t] wih0^T + h0[t-1] whh0^T); stages x[t+1] ----
    const int mt = wid;
    half8 ai0[2], ah0[8];
    loadw8(ah0, whh0, mt * 32 + l31, hf);
#pragma unroll
    for (int kc = 0; kc < 2; ++kc) {  // wih0: K=28 padded to 32 with zeros
      half8 f;
#pragma unroll
      for (int j = 0; j < 8; ++j) {
        const int k = kc * 16 + hf * 8 + j;
        f[j] = (k < IN_) ? (half_t)wih0[(mt * 32 + l31) * IN_ + k] : (half_t)0.0f;
      }
      ai0[kc] = f;
    }
    const int xrow = tid >> 3, xch = tid & 7;  // tid<256: rows xrow, xrow+32
    for (int t = 0; t < T_; ++t) {
      const bool xact = (xch < 7) && (t + 1 < T_);
      f32x4 xq0, xq1;
      if (xact) {  // issue global loads before any LDS wait (hide HBM latency)
        const float* xp = x + (size_t)(t + 1) * IN_ + xch * 4;
        xq0 = *(const f32x4*)(xp + (size_t)(b0 + xrow) * (T_ * IN_));
        xq1 = *(const f32x4*)(xp + (size_t)(b0 + xrow + 32) * (T_ * IN_));
      }
      wait4(F0, t);  // h0[t-1] + x[t] visible (from all 4 L0 waves)
      {
        const half_t* bx0 = XB(t & 1) + l31 * XSTR + hf * 8;
        const half_t* bx1 = XB(t & 1) + (32 + l31) * XSTR + hf * 8;
        const int sr = (t + 2) % 3;  // slot of h0[t-1]
        const half_t* bh0 = HB0(sr) + l31 * HSTR + hf * 8;
        const half_t* bh1 = HB0(sr) + (32 + l31) * HSTR + hf * 8;
        f32x16 a0 = {}, a1 = {};
#pragma unroll
        for (int kc = 0; kc < 2; ++kc) {
          a0 = mfma(ai0[kc], frag(bx0, kc), a0);
          a1 = mfma(ai0[kc], frag(bx1, kc), a1);
        }
#pragma unroll
        for (int kc = 0; kc < 8; ++kc) {
          a0 = mfma(ah0[kc], frag(bh0, kc), a0);
          a1 = mfma(ah0[kc], frag(bh1, kc), a1);
        }
        wait4(F1, t - 2);  // L1 done reading h0[t-3] -> slot t%3 safe to overwrite
        epi1(HB0(t % 3), bias, a0, mt * 32, 0,  l31, hf);
        epi1(HB0(t % 3), bias, a1, mt * 32, 32, l31, hf);
      }
      if (xact) {
        half4v h4a, h4b;
#pragma unroll
        for (int j = 0; j < 4; ++j) { h4a[j] = (half_t)xq0[j]; h4b[j] = (half_t)xq1[j]; }
        *(half4v*)&XB((t + 1) & 1)[xrow * XSTR + xch * 4] = h4a;
        *(half4v*)&XB((t + 1) & 1)[(xrow + 32) * XSTR + xch * 4] = h4b;
      }
      bump(&F0[mt], t + 1, lane);
    }
  } else if (wid < 8) {
    // ---- L1: h1[t] = relu(b1 + h0[t] wih1^T + h1[t-1] whh1^T) ----
    const int mt1 = wid - 4;
    half8 wi[8], wh[8];
    loadw8(wi, wih1, mt1 * 32 + l31, hf);
    loadw8(wh, whh1, mt1 * 32 + l31, hf);
    for (int t = 0; t < T_; ++t) {
      wait4(F1, t);      // h1[t-1] (own group)
      wait4(F0, t + 1);  // h0[t] (producer group)
      {
        const int si = t % 3;        // slot of h0[t]
        const int sr = (t + 2) % 3;  // slot of h1[t-1]
        const half_t* bi0 = HB0(si) + l31 * HSTR + hf * 8;
        const half_t* bi1 = HB0(si) + (32 + l31) * HSTR + hf * 8;
        const half_t* br0 = HB1(sr) + l31 * HSTR + hf * 8;
        const half_t* br1 = HB1(sr) + (32 + l31) * HSTR + hf * 8;
        f32x16 a0 = {}, a1 = {};
#pragma unroll
        for (int kc = 0; kc < 8; ++kc) {
          a0 = mfma(wi[kc], frag(bi0, kc), a0);
          a1 = mfma(wi[kc], frag(bi1, kc), a1);
        }
#pragma unroll
        for (int kc = 0; kc < 8; ++kc) {
          a0 = mfma(wh[kc], frag(br0, kc), a0);
          a1 = mfma(wh[kc], frag(br1, kc), a1);
        }
        wait4(F2, t - 2);  // L2 done reading h1[t-3] -> slot t%3 safe
        epi1(HB1(t % 3), bias + H_, a0, mt1 * 32, 0,  l31, hf);
        epi1(HB1(t % 3), bias + H_, a1, mt1 * 32, 32, l31, hf);
      }
      bump(&F1[mt1], t + 1, lane);
    }
  } else {
    // ---- L2: h2[t] = relu(b2 + h1[t] wih2^T + h2[t-1] whh2^T) ----
    const int mt2 = wid - 8;
    half8 wi[8], wh[8];
    loadw8(wi, wih2, mt2 * 32 + l31, hf);
    loadw8(wh, whh2, mt2 * 32 + l31, hf);
    for (int t = 0; t < T_; ++t) {
      wait4(F2, t);      // h2[t-1] (own group; also slot safety, D=2)
      wait4(F1, t + 1);  // h1[t]
      {
        const int si = t % 3;       // slot of h1[t]
        const int sr = (t + 1) & 1; // slot of h2[t-1]
        const half_t* bi0 = HB1(si) + l31 * HSTR + hf * 8;
        const half_t* bi1 = HB1(si) + (32 + l31) * HSTR + hf * 8;
        const half_t* br0 = HB2(sr) + l31 * HSTR + hf * 8;
        const half_t* br1 = HB2(sr) + (32 + l31) * HSTR + hf * 8;
        f32x16 a0 = {}, a1 = {};
#pragma unroll
        for (int kc = 0; kc < 8; ++kc) {
          a0 = mfma(wi[kc], frag(bi0, kc), a0);
          a1 = mfma(wi[kc], frag(bi1, kc), a1);
        }
#pragma unroll
        for (int kc = 0; kc < 8; ++kc) {
          a0 = mfma(wh[kc], frag(br0, kc), a0);
          a1 = mfma(wh[kc], frag(br1, kc), a1);
        }
        epi1(HB2(t & 1), bias + 2 * H_, a0, mt2 * 32, 0,  l31, hf);
        epi1(HB2(t & 1), bias + 2 * H_, a1, mt2 * 32, 32, l31, hf);
      }
      bump(&F2[mt2], t + 1, lane);
    }
  }
  __syncthreads();  // join all groups; h2[T-1] visible

  // ---- FC head: out[b][c] = h2_last[b] . fcw[c] + fcb[c] ----
  if (tid < 512) {
    const half_t* h2f = HB2((T_ - 1) & 1);
    const int row = tid >> 3, q = tid & 7;
    for (int c = q; c < C_; c += 8) {
      float s = fcb[c];
      const float* wp = fcw + c * H_;
#pragma unroll
      for (int k = 0; k < H_; k += 8) {
        const half8 hv = *(const half8*)&h2f[row * HSTR + k];
#pragma unroll
        for (int j = 0; j < 8; ++j) s += (float)hv[j] * wp[k + j];
      }
      out[(size_t)(b0 + row) * C_ + c] = s;
    }
  }
#undef HB0
#undef HB1
#undef HB2
#undef XB
}

extern "C" void kernel_launch(void* const* d_in, const int* in_sizes, int n_in,
                              void* d_out, int out_size, void* d_ws, size_t ws_size,
                              hipStream_t stream)
{
  const float* x    = (const float*)d_in[0];
  const float* wih0 = (const float*)d_in[1];
  const float* whh0 = (const float*)d_in[2];
  const float* bih0 = (const float*)d_in[3];
  const float* bhh0 = (const float*)d_in[4];
  const float* wih1 = (const float*)d_in[5];
  const float* whh1 = (const float*)d_in[6];
  const float* bih1 = (const float*)d_in[7];
  const float* bhh1 = (const float*)d_in[8];
  const float* wih2 = (const float*)d_in[9];
  const float* whh2 = (const float*)d_in[10];
  const float* bih2 = (const float*)d_in[11];
  const float* bhh2 = (const float*)d_in[12];
  const float* fcw  = (const float*)d_in[13];
  const float* fcb  = (const float*)d_in[14];
  float* out = (float*)d_out;

  (void)hipFuncSetAttribute((const void*)rnn_pipe,
                            hipFuncAttributeMaxDynamicSharedMemorySize, (int)SM_BYTES);

  rnn_pipe<<<B_ / BT, NT, SM_BYTES, stream>>>(x,
      wih0, whh0, bih0, bhh0,
      wih1, whh1, bih1, bhh1,
      wih2, whh2, bih2, bhh2,
      fcw, fcb, out);
}